// Round 1
// baseline (278.019 us; speedup 1.0000x reference)
//
#include <hip/hip_runtime.h>
#include <hip/hip_bf16.h>
#include <math.h>
#include <stdint.h>

// Problem constants
#define NCH   8
#define DNX   128
#define DNY   128
#define KPTS  16384

typedef __attribute__((ext_vector_type(8))) short bf16x8;   // MFMA A/B frag (8 bf16)
typedef __attribute__((ext_vector_type(4))) float f32x4;    // MFMA C/D frag

typedef const __attribute__((address_space(1))) unsigned int* gp_t;
typedef __attribute__((address_space(3))) unsigned int* lp_t;

// pack two fp32 -> one uint32 of two bf16 (RNE) via v_cvt_pk_bf16_f32
__device__ __forceinline__ uint32_t pkbf(float lo, float hi) {
    union { __hip_bfloat162 h; uint32_t u; } v;
    v.h = __float22bfloat162_rn(make_float2(lo, hi));
    return v.u;
}

// Sum over each 16-lane row via DPP (pure VALU — keeps LDS pipe free).
__device__ __forceinline__ float dpp_sum16(float v) {
    v += __int_as_float(__builtin_amdgcn_update_dpp(0, __float_as_int(v), 0xB1,  0xF, 0xF, true));
    v += __int_as_float(__builtin_amdgcn_update_dpp(0, __float_as_int(v), 0x4E,  0xF, 0xF, true));
    v += __int_as_float(__builtin_amdgcn_update_dpp(0, __float_as_int(v), 0x141, 0xF, 0xF, true));
    v += __int_as_float(__builtin_amdgcn_update_dpp(0, __float_as_int(v), 0x140, 0xF, 0xF, true));
    return v;
}

// ---------------------------------------------------------------------------
// Prep: img (fp32 planar re/im) -> B_pre (bf16, per-channel 64KB image in the
// exact LDS layout). Logical B[x][col], col = 2y+s (s=0:re, 1:im). Address:
// (256*col + 64*t4 + 16*q) ^ (16*(col&7)), x = 32*t4 + 8*q + j, +2*j.
// (mapping verified rounds 4-6 of prior session)
// ---------------------------------------------------------------------------
__global__ __launch_bounds__(256) void prep_kernel(
    const float* __restrict__ img_real,
    const float* __restrict__ img_imag,
    unsigned short* __restrict__ B_pre)
{
    int tid = blockIdx.x * 256 + threadIdx.x;   // 32768 threads total
    int y  = tid & 127;
    int xc = (tid >> 7) & 15;                   // which 8-x chunk
    int s  = (tid >> 11) & 1;
    int c  = tid >> 12;
    int t4 = xc >> 2, q = xc & 3;
    int x0 = 32 * t4 + 8 * q;
    const float* src = (s ? img_imag : img_real) + c * (DNX * DNY) + y;
    float f[8];
    #pragma unroll
    for (int j = 0; j < 8; ++j) f[j] = src[(x0 + j) * DNY];
    int col  = 2 * y + s;
    int dest = (256 * col + 64 * t4 + 16 * q) ^ (16 * (col & 7));
    uint4 val;
    val.x = pkbf(f[0], f[1]);
    val.y = pkbf(f[2], f[3]);
    val.z = pkbf(f[4], f[5]);
    val.w = pkbf(f[6], f[7]);
    *(uint4*)((char*)B_pre + (size_t)c * 65536 + dest) = val;
}

// ---------------------------------------------------------------------------
// Main: block = 4 waves, each wave owns 32 k (2 k-groups of 16).
// Grid (128 kblocks, 4 chan-groups of 2 channels).
//
// This version (vs prior session's 2-full-barrier-per-channel structure):
//  * T3/T4: channel staged as two 32KB halves into buf0/buf1 (same addresses
//    as before: ct 0-7 -> bytes [0,32K), ct 8-15 -> [32K,64K)). Next chunk's
//    global_load_lds issued right after the read-done barrier; waits are
//    counted (vmcnt(8)), raw s_barrier + sched_barrier(0) fences, NO
//    __syncthreads vmcnt(0) drain anywhere in the loop.
//  * Manual ILP pipeline: MFMAs of ct+1 (acc set B) are issued before the
//    stage-2 VALU of ct (acc set A), so VALU overlaps the matrix pipe.
//  * acc zero-init via MFMA C-operand (no v_mov zeroing per ct).
//  * ds addresses: two pre-XOR'd base pointers (t4 even/odd); all 64 reads
//    per channel use compile-time immediate offsets (4096*ct + 128*(t4>>1)).
//    Valid because Mx only touches bits 4-6, which carry-free hold
//    16*quad + 64*(t4&1).
//  * T5: s_setprio(1) around each 16-MFMA cluster.
// vmcnt audit (stores count in vmcnt on gfx9-lineage!):
//   entry: issue c0h0(8), c0h1(8)              [trj loads issued BEFORE these]
//   cc0 top:  vmcnt(8)  -> c0h0 done
//   cc0 mid:  issue c1h0 after read-done bar; vmcnt(8) -> c0h1 done
//   cc0 end:  issue c1h1 after read-done bar; epilogue stores issue after
//   cc1 top:  vmcnt(0)  -> c1h0 (and c1h1 + stores) done
//   cc1 mid:  vmcnt(0)  -> no-op
// ---------------------------------------------------------------------------

#define SCHED0() __builtin_amdgcn_sched_barrier(0)
#define SBAR()   __builtin_amdgcn_s_barrier()

#define ISSUE(c_, h_) do { \
    const char* g_ = (const char*)B_pre + ((size_t)(c_) << 16) + ((h_) << 15) + (w << 13) + (lane << 4); \
    char* l_ = (char*)&Bl[0] + ((h_) << 15) + (w << 13); \
    _Pragma("unroll") \
    for (int i_ = 0; i_ < 8; ++i_) \
        __builtin_amdgcn_global_load_lds((gp_t)(const void*)(g_ + (i_ << 10)), \
                                         (lp_t)(void*)(l_ + (i_ << 10)), 16, 0, 0); \
} while (0)

// 4 ds_read_b128 (imm offsets) + 16 MFMA; first t4 writes acc from ZER (no
// zero-init movs). Chains acc1[0],acc2[0],acc1[1],acc2[1] interleaved -> dep
// distance 4 MFMAs.
#define MFMA_CT(ct_, q1, q2) do { \
    __builtin_amdgcn_s_setprio(1); \
    bf16x8 b0_ = *(const bf16x8*)(pe + 4096*(ct_)); \
    bf16x8 b1_ = *(const bf16x8*)(po + 4096*(ct_)); \
    bf16x8 b2_ = *(const bf16x8*)(pe + 4096*(ct_) + 128); \
    bf16x8 b3_ = *(const bf16x8*)(po + 4096*(ct_) + 128); \
    q1[0] = __builtin_amdgcn_mfma_f32_16x16x32_bf16(pxr[0][0], b0_, ZER,   0,0,0); \
    q2[0] = __builtin_amdgcn_mfma_f32_16x16x32_bf16(pxi[0][0], b0_, ZER,   0,0,0); \
    q1[1] = __builtin_amdgcn_mfma_f32_16x16x32_bf16(pxr[1][0], b0_, ZER,   0,0,0); \
    q2[1] = __builtin_amdgcn_mfma_f32_16x16x32_bf16(pxi[1][0], b0_, ZER,   0,0,0); \
    q1[0] = __builtin_amdgcn_mfma_f32_16x16x32_bf16(pxr[0][1], b1_, q1[0], 0,0,0); \
    q2[0] = __builtin_amdgcn_mfma_f32_16x16x32_bf16(pxi[0][1], b1_, q2[0], 0,0,0); \
    q1[1] = __builtin_amdgcn_mfma_f32_16x16x32_bf16(pxr[1][1], b1_, q1[1], 0,0,0); \
    q2[1] = __builtin_amdgcn_mfma_f32_16x16x32_bf16(pxi[1][1], b1_, q2[1], 0,0,0); \
    q1[0] = __builtin_amdgcn_mfma_f32_16x16x32_bf16(pxr[0][2], b2_, q1[0], 0,0,0); \
    q2[0] = __builtin_amdgcn_mfma_f32_16x16x32_bf16(pxi[0][2], b2_, q2[0], 0,0,0); \
    q1[1] = __builtin_amdgcn_mfma_f32_16x16x32_bf16(pxr[1][2], b2_, q1[1], 0,0,0); \
    q2[1] = __builtin_amdgcn_mfma_f32_16x16x32_bf16(pxi[1][2], b2_, q2[1], 0,0,0); \
    q1[0] = __builtin_amdgcn_mfma_f32_16x16x32_bf16(pxr[0][3], b3_, q1[0], 0,0,0); \
    q2[0] = __builtin_amdgcn_mfma_f32_16x16x32_bf16(pxi[0][3], b3_, q2[0], 0,0,0); \
    q1[1] = __builtin_amdgcn_mfma_f32_16x16x32_bf16(pxr[1][3], b3_, q1[1], 0,0,0); \
    q2[1] = __builtin_amdgcn_mfma_f32_16x16x32_bf16(pxi[1][3], b3_, q2[1], 0,0,0); \
    __builtin_amdgcn_s_setprio(0); \
} while (0)

// lane-local combine with rotor advance; call order == ct order.
#define STAGE2(q1, q2) do { \
    _Pragma("unroll") \
    for (int kg_ = 0; kg_ < 2; ++kg_) { \
        _Pragma("unroll") \
        for (int r_ = 0; r_ < 4; ++r_) { \
            const int i_ = kg_ * 4 + r_; \
            float a1_ = q1[kg_][r_], a2_ = q2[kg_][r_]; \
            F[i_] = fmaf(a1_,  cb[i_], F[i_]); \
            F[i_] = fmaf(-a2_, sb[i_], F[i_]); \
            G[i_] = fmaf(a1_,  sb[i_], G[i_]); \
            G[i_] = fmaf(a2_,  cb[i_], G[i_]); \
            float tz_ = cb[i_] * dr[i_] - sb[i_] * di[i_]; \
            sb[i_]   = fmaf(cb[i_], di[i_], sb[i_] * dr[i_]); \
            cb[i_]   = tz_; \
        } } \
} while (0)

__global__ __launch_bounds__(256, 2) void nudft_mfma_kernel(
    const float* __restrict__ trj,
    const unsigned short* __restrict__ B_pre,
    float* __restrict__ out)
{
    __shared__ __align__(16) unsigned short Bl[32768];   // 64 KB = 2 x 32 KB halves

    const int t    = threadIdx.x;
    const int w    = t >> 6;          // wave 0..3
    const int lane = t & 63;
    const int m    = lane & 15;       // MFMA row (A) / col (C) index
    const int quad = (lane >> 4) & 3;
    const int spar = m & 1;           // col parity: 0 = re-col, 1 = im-col
    const int kb   = blockIdx.x;      // 0..127
    const int cg   = blockIdx.y;      // 0..3 -> channels 2cg, 2cg+1
    const int k0w  = kb * 128 + w * 32;

    // ---- trj loads FIRST so the DMA issues below stay oldest-after them
    // (keeps the counted-vmcnt arithmetic exact; safe either way).
    float trjx[2], tyv[8];
    #pragma unroll
    for (int kg = 0; kg < 2; ++kg)
        trjx[kg] = trj[2 * (k0w + kg * 16 + m) + 0];
    #pragma unroll
    for (int kg = 0; kg < 2; ++kg)
        #pragma unroll
        for (int r = 0; r < 4; ++r)
            tyv[kg * 4 + r] = trj[2 * (k0w + kg * 16 + quad * 4 + r) + 1];
    SCHED0();

    // ---- prefetch channel 2cg: both 32KB halves in flight during trig setup
    {
        const int c0 = cg * 2;
        ISSUE(c0, 0);
        ISSUE(c0, 1);
    }
    SCHED0();

    // ---- A fragments (px) via incremental rotation + packed bf16 cvt:
    // A[m][x = 32*t4 + 8*quad + j]; theta(x) = d1*(x-64) pi-units, d1 = -trjx/64
    bf16x8 pxr[2][4], pxi[2][4];
    #pragma unroll
    for (int kg = 0; kg < 2; ++kg) {
        const float d1 = -trjx[kg] * (1.0f / 64.0f);
        float s1, c1;  sincospif(d1, &s1, &c1);            // rot per +1 x
        float s32, c32; sincospif(d1 * 32.0f, &s32, &c32); // rot per +32 x (t4 step)
        float ps, pc;  sincospif(d1 * (float)(8 * quad - 64), &ps, &pc);
        #pragma unroll
        for (int t4 = 0; t4 < 4; ++t4) {
            float qc = pc, qs = ps;
            float fc[8], fs[8];
            #pragma unroll
            for (int j = 0; j < 8; ++j) {
                fc[j] = qc; fs[j] = qs;
                if (j < 7) {
                    float tq = qc * c1 - qs * s1;
                    qs = fmaf(qc, s1, qs * c1);
                    qc = tq;
                }
            }
            uint32_t* pr = (uint32_t*)&pxr[kg][t4];
            uint32_t* pi = (uint32_t*)&pxi[kg][t4];
            #pragma unroll
            for (int p = 0; p < 4; ++p) {
                pr[p] = pkbf(fc[2 * p], fc[2 * p + 1]);
                pi[p] = pkbf(fs[2 * p], fs[2 * p + 1]);
            }
            if (t4 < 3) {
                float tp = pc * c32 - ps * s32;
                ps = fmaf(pc, s32, ps * c32);
                pc = tp;
            }
        }
    }

    // ---- stage-2 rotor init. Lane element idx=(kg,r): k = k0w+kg*16+quad*4+r,
    // y = ct*8 + ybase, ybase = m>>1. (cb,sb) = cos/sin(pi * -ty*(y-64)/64);
    // per-ct step rotor (dr,di) = cos/sin(pi * -ty/8). Parity-independent.
    const int ybase = m >> 1;
    float cb0[8], sb0[8], dr[8], di[8];
    #pragma unroll
    for (int idx = 0; idx < 8; ++idx) {
        float ty = tyv[idx];
        float sbv, cbv; sincospif(-ty * (float)(ybase - 64) * (1.0f / 64.0f), &sbv, &cbv);
        cb0[idx] = cbv; sb0[idx] = sbv;
        float sd, cd; sincospif(-ty * 0.125f, &sd, &cd);
        dr[idx] = cd; di[idx] = sd;
    }

    // two pre-XOR'd LDS bases: addr(ct,t4) = (t4&1 ? po : pe)
    //                                        + 4096*ct + 128*(t4>>1)
    const int A0 = 256 * m + 16 * quad;
    const int Mx = 16 * (m & 7);
    const char* pe = (const char*)&Bl[0] + (A0 ^ Mx);
    const char* po = (const char*)&Bl[0] + ((A0 + 64) ^ Mx);
    const f32x4 ZER = {0.f, 0.f, 0.f, 0.f};

    float F[8], G[8], cb[8], sb[8];
    f32x4 xA1[2], xA2[2], xB1[2], xB2[2];

    #pragma unroll 1
    for (int cc = 0; cc < 2; ++cc) {
        const int c = cg * 2 + cc;
        #pragma unroll
        for (int i = 0; i < 8; ++i) {
            F[i] = 0.f; G[i] = 0.f; cb[i] = cb0[i]; sb[i] = sb0[i];
        }

        // === buf0 ready cluster ===
        if (cc == 0) { asm volatile("s_waitcnt vmcnt(8)" ::: "memory"); }
        else         { asm volatile("s_waitcnt vmcnt(0)" ::: "memory"); }
        SCHED0(); SBAR(); SCHED0();

        // === ct 0..7 from buf0, acc-pipelined ===
        MFMA_CT(0, xA1, xA2);
        MFMA_CT(1, xB1, xB2); STAGE2(xA1, xA2);   // ct0
        MFMA_CT(2, xA1, xA2); STAGE2(xB1, xB2);   // ct1
        MFMA_CT(3, xB1, xB2); STAGE2(xA1, xA2);   // ct2
        MFMA_CT(4, xA1, xA2); STAGE2(xB1, xB2);   // ct3
        MFMA_CT(5, xB1, xB2); STAGE2(xA1, xA2);   // ct4
        MFMA_CT(6, xA1, xA2); STAGE2(xB1, xB2);   // ct5
        MFMA_CT(7, xB1, xB2); STAGE2(xA1, xA2);   // ct6

        // === buf0 read-done; refill it with next channel's half0 ===
        asm volatile("s_waitcnt lgkmcnt(0)" ::: "memory");
        SCHED0(); SBAR(); SCHED0();
        if (cc == 0) { ISSUE(cg * 2 + 1, 0); }
        SCHED0();

        // === buf1 ready cluster ===
        if (cc == 0) { asm volatile("s_waitcnt vmcnt(8)" ::: "memory"); }
        else         { asm volatile("s_waitcnt vmcnt(0)" ::: "memory"); }
        SCHED0(); SBAR(); SCHED0();

        // === ct 8..15 from buf1 ===
        MFMA_CT(8,  xA1, xA2); STAGE2(xB1, xB2);  // ct7
        MFMA_CT(9,  xB1, xB2); STAGE2(xA1, xA2);  // ct8
        MFMA_CT(10, xA1, xA2); STAGE2(xB1, xB2);  // ct9
        MFMA_CT(11, xB1, xB2); STAGE2(xA1, xA2);  // ct10
        MFMA_CT(12, xA1, xA2); STAGE2(xB1, xB2);  // ct11
        MFMA_CT(13, xB1, xB2); STAGE2(xA1, xA2);  // ct12
        MFMA_CT(14, xA1, xA2); STAGE2(xB1, xB2);  // ct13
        MFMA_CT(15, xB1, xB2); STAGE2(xA1, xA2);  // ct14
        STAGE2(xB1, xB2);                          // ct15

        // === buf1 read-done; refill with next channel's half1 ===
        asm volatile("s_waitcnt lgkmcnt(0)" ::: "memory");
        SCHED0(); SBAR(); SCHED0();
        if (cc == 0) { ISSUE(cg * 2 + 1, 1); }
        SCHED0();

        // epilogue: per-lane parity assignment, 16-lane DPP reduction (VALU)
        #pragma unroll
        for (int idx = 0; idx < 8; ++idx) {
            float kre_p = spar ? -G[idx] : F[idx];
            float kim_p = spar ?  F[idx] : G[idx];
            float kre_s = dpp_sum16(kre_p);
            float kim_s = dpp_sum16(kim_p);
            if (m == 0) {
                int kg = idx >> 2, r = idx & 3;
                int k = k0w + kg * 16 + quad * 4 + r;
                out[(size_t)c * KPTS + k]                      = kre_s;
                out[(size_t)NCH * KPTS + (size_t)c * KPTS + k] = kim_s;
            }
        }
    }
}

extern "C" void kernel_launch(void* const* d_in, const int* in_sizes, int n_in,
                              void* d_out, int out_size, void* d_ws, size_t ws_size,
                              hipStream_t stream)
{
    const float* img_real = (const float*)d_in[0];  // (8,128,128) fp32
    const float* img_imag = (const float*)d_in[1];  // (8,128,128) fp32
    const float* trj      = (const float*)d_in[2];  // (16384,2) fp32
    float* out = (float*)d_out;                      // planar: re block then im block
    unsigned short* B_pre = (unsigned short*)d_ws;   // 512 KB bf16 pre-swizzled img

    prep_kernel<<<128, 256, 0, stream>>>(img_real, img_imag, B_pre);
    nudft_mfma_kernel<<<dim3(128, 4), 256, 0, stream>>>(trj, B_pre, out);
}

// Round 2
// 79.836 us; speedup vs baseline: 3.4824x; 3.4824x over previous
//
#include <hip/hip_runtime.h>
#include <hip/hip_bf16.h>
#include <math.h>
#include <stdint.h>

// Problem constants
#define NCH   8
#define DNX   128
#define DNY   128
#define KPTS  16384

typedef __attribute__((ext_vector_type(8))) short bf16x8;   // MFMA A/B frag (8 bf16)
typedef __attribute__((ext_vector_type(4))) float f32x4;    // MFMA C/D frag

typedef const __attribute__((address_space(1))) unsigned int* gp_t;
typedef __attribute__((address_space(3))) unsigned int* lp_t;

// pack two fp32 -> one uint32 of two bf16 (RNE) via v_cvt_pk_bf16_f32
__device__ __forceinline__ uint32_t pkbf(float lo, float hi) {
    union { __hip_bfloat162 h; uint32_t u; } v;
    v.h = __float22bfloat162_rn(make_float2(lo, hi));
    return v.u;
}

// Sum over each 16-lane row via DPP (pure VALU — keeps LDS pipe free).
__device__ __forceinline__ float dpp_sum16(float v) {
    v += __int_as_float(__builtin_amdgcn_update_dpp(0, __float_as_int(v), 0xB1,  0xF, 0xF, true));
    v += __int_as_float(__builtin_amdgcn_update_dpp(0, __float_as_int(v), 0x4E,  0xF, 0xF, true));
    v += __int_as_float(__builtin_amdgcn_update_dpp(0, __float_as_int(v), 0x141, 0xF, 0xF, true));
    v += __int_as_float(__builtin_amdgcn_update_dpp(0, __float_as_int(v), 0x140, 0xF, 0xF, true));
    return v;
}

// ---------------------------------------------------------------------------
// Prep: img (fp32 planar re/im) -> B_pre (bf16, per-channel 64KB image in the
// exact LDS layout). Logical B[x][col], col = 2y+s (s=0:re, 1:im). Address:
// (256*col + 64*t4 + 16*q) ^ (16*(col&7)), x = 32*t4 + 8*q + j, +2*j.
// ---------------------------------------------------------------------------
__global__ __launch_bounds__(256) void prep_kernel(
    const float* __restrict__ img_real,
    const float* __restrict__ img_imag,
    unsigned short* __restrict__ B_pre)
{
    int tid = blockIdx.x * 256 + threadIdx.x;   // 32768 threads total
    int y  = tid & 127;
    int xc = (tid >> 7) & 15;                   // which 8-x chunk
    int s  = (tid >> 11) & 1;
    int c  = tid >> 12;
    int t4 = xc >> 2, q = xc & 3;
    int x0 = 32 * t4 + 8 * q;
    const float* src = (s ? img_imag : img_real) + c * (DNX * DNY) + y;
    float f[8];
    #pragma unroll
    for (int j = 0; j < 8; ++j) f[j] = src[(x0 + j) * DNY];
    int col  = 2 * y + s;
    int dest = (256 * col + 64 * t4 + 16 * q) ^ (16 * (col & 7));
    uint4 val;
    val.x = pkbf(f[0], f[1]);
    val.y = pkbf(f[2], f[3]);
    val.z = pkbf(f[4], f[5]);
    val.w = pkbf(f[6], f[7]);
    *(uint4*)((char*)B_pre + (size_t)c * 65536 + dest) = val;
}

// ---------------------------------------------------------------------------
// Main: block = 4 waves, each wave owns 32 k (2 k-groups of 16).
// Grid (128 kblocks, 4 chan-groups of 2 channels).
//
// Round-2 structure (round-1's acc double-buffer SPILLED — 256MB scratch
// traffic; reverted). Register-cheap pipeline pieces kept:
//  * channel staged as two 32KB halves; next chunk's global_load_lds issued
//    right after the read-done barrier; waits are counted (vmcnt(8)); raw
//    s_barrier; no vmcnt(0)+lgkmcnt(0) full drains inside the loop.
//  * both halves of channel 0 prefetched before the trig setup.
//  * single acc set, STAGE2 immediately after each ct (prior 80us register
//    profile, which fit without spills).
//  * ds addresses: two pre-XOR'd bases (t4 even/odd); offsets are
//    4096*ct + 128*(t4>>1). Valid because Mx only touches bits 4-6, which
//    carry-free hold 16*quad + 64*(t4&1).
//  * acc zero-init via MFMA C-operand; s_setprio(1) around MFMA cluster.
// vmcnt audit (global_load_lds and stores both count in vmcnt):
//   entry: trj loads (drained by use), issue c0h0(8), c0h1(8)
//   cc0 buf0-ready: vmcnt(8)  -> c0h0 done     (c0h1 in flight)
//   cc0 mid: lgkm0+bar, ISSUE c1h0 -> outstanding c0h1(8)+c1h0(8)
//   cc0 buf1-ready: vmcnt(8)  -> c0h1 done     (c1h0 in flight)
//   cc0 end: lgkm0+bar, ISSUE c1h1; epilogue stores issue after
//   cc1 buf0-ready: vmcnt(0)  -> everything done (conservative, cheap: c1h1
//                                 had the whole epilogue to land)
//   cc1 buf1-ready: vmcnt(0)  -> no-op
// ---------------------------------------------------------------------------

#define SCHED0() __builtin_amdgcn_sched_barrier(0)
#define SBAR()   __builtin_amdgcn_s_barrier()

#define ISSUE(c_, h_) do { \
    const char* g_ = (const char*)B_pre + ((size_t)(c_) << 16) + ((h_) << 15) + (w << 13) + (lane << 4); \
    char* l_ = (char*)&Bl[0] + ((h_) << 15) + (w << 13); \
    _Pragma("unroll") \
    for (int i_ = 0; i_ < 8; ++i_) \
        __builtin_amdgcn_global_load_lds((gp_t)(const void*)(g_ + (i_ << 10)), \
                                         (lp_t)(void*)(l_ + (i_ << 10)), 16, 0, 0); \
} while (0)

// 8 cts: per ct, 4 ds_read_b128 (base+imm) + 16 MFMA (ZER C-init) + STAGE2.
#define RUN8(ct0_) do { \
    _Pragma("unroll 2") \
    for (int ct = (ct0_); ct < (ct0_) + 8; ++ct) { \
        bf16x8 b0_ = *(const bf16x8*)(pe + 4096 * ct); \
        bf16x8 b1_ = *(const bf16x8*)(po + 4096 * ct); \
        bf16x8 b2_ = *(const bf16x8*)(pe + 4096 * ct + 128); \
        bf16x8 b3_ = *(const bf16x8*)(po + 4096 * ct + 128); \
        f32x4 a1k0, a2k0, a1k1, a2k1; \
        __builtin_amdgcn_s_setprio(1); \
        a1k0 = __builtin_amdgcn_mfma_f32_16x16x32_bf16(pxr[0][0], b0_, ZER,  0,0,0); \
        a2k0 = __builtin_amdgcn_mfma_f32_16x16x32_bf16(pxi[0][0], b0_, ZER,  0,0,0); \
        a1k1 = __builtin_amdgcn_mfma_f32_16x16x32_bf16(pxr[1][0], b0_, ZER,  0,0,0); \
        a2k1 = __builtin_amdgcn_mfma_f32_16x16x32_bf16(pxi[1][0], b0_, ZER,  0,0,0); \
        a1k0 = __builtin_amdgcn_mfma_f32_16x16x32_bf16(pxr[0][1], b1_, a1k0, 0,0,0); \
        a2k0 = __builtin_amdgcn_mfma_f32_16x16x32_bf16(pxi[0][1], b1_, a2k0, 0,0,0); \
        a1k1 = __builtin_amdgcn_mfma_f32_16x16x32_bf16(pxr[1][1], b1_, a1k1, 0,0,0); \
        a2k1 = __builtin_amdgcn_mfma_f32_16x16x32_bf16(pxi[1][1], b1_, a2k1, 0,0,0); \
        a1k0 = __builtin_amdgcn_mfma_f32_16x16x32_bf16(pxr[0][2], b2_, a1k0, 0,0,0); \
        a2k0 = __builtin_amdgcn_mfma_f32_16x16x32_bf16(pxi[0][2], b2_, a2k0, 0,0,0); \
        a1k1 = __builtin_amdgcn_mfma_f32_16x16x32_bf16(pxr[1][2], b2_, a1k1, 0,0,0); \
        a2k1 = __builtin_amdgcn_mfma_f32_16x16x32_bf16(pxi[1][2], b2_, a2k1, 0,0,0); \
        a1k0 = __builtin_amdgcn_mfma_f32_16x16x32_bf16(pxr[0][3], b3_, a1k0, 0,0,0); \
        a2k0 = __builtin_amdgcn_mfma_f32_16x16x32_bf16(pxi[0][3], b3_, a2k0, 0,0,0); \
        a1k1 = __builtin_amdgcn_mfma_f32_16x16x32_bf16(pxr[1][3], b3_, a1k1, 0,0,0); \
        a2k1 = __builtin_amdgcn_mfma_f32_16x16x32_bf16(pxi[1][3], b3_, a2k1, 0,0,0); \
        __builtin_amdgcn_s_setprio(0); \
        _Pragma("unroll") \
        for (int r_ = 0; r_ < 4; ++r_) { \
            _Pragma("unroll") \
            for (int kg_ = 0; kg_ < 2; ++kg_) { \
                const int i_ = kg_ * 4 + r_; \
                float a1_ = kg_ ? a1k1[r_] : a1k0[r_]; \
                float a2_ = kg_ ? a2k1[r_] : a2k0[r_]; \
                F[i_] = fmaf(a1_,  cb[i_], F[i_]); \
                F[i_] = fmaf(-a2_, sb[i_], F[i_]); \
                G[i_] = fmaf(a1_,  sb[i_], G[i_]); \
                G[i_] = fmaf(a2_,  cb[i_], G[i_]); \
                float tz_ = cb[i_] * dr[i_] - sb[i_] * di[i_]; \
                sb[i_]   = fmaf(cb[i_], di[i_], sb[i_] * dr[i_]); \
                cb[i_]   = tz_; \
            } } \
    } \
} while (0)

__global__ __launch_bounds__(256, 2) void nudft_mfma_kernel(
    const float* __restrict__ trj,
    const unsigned short* __restrict__ B_pre,
    float* __restrict__ out)
{
    __shared__ __align__(16) unsigned short Bl[32768];   // 64 KB = 2 x 32 KB halves

    const int t    = threadIdx.x;
    const int w    = t >> 6;          // wave 0..3
    const int lane = t & 63;
    const int m    = lane & 15;       // MFMA row (A) / col (C) index
    const int quad = (lane >> 4) & 3;
    const int spar = m & 1;           // col parity: 0 = re-col, 1 = im-col
    const int kb   = blockIdx.x;      // 0..127
    const int cg   = blockIdx.y;      // 0..3 -> channels 2cg, 2cg+1
    const int k0w  = kb * 128 + w * 32;

    // ---- trj loads FIRST so the DMA issues below stay oldest-after them
    // (keeps the counted-vmcnt arithmetic exact).
    float trjx[2], tyv[8];
    #pragma unroll
    for (int kg = 0; kg < 2; ++kg)
        trjx[kg] = trj[2 * (k0w + kg * 16 + m) + 0];
    #pragma unroll
    for (int kg = 0; kg < 2; ++kg)
        #pragma unroll
        for (int r = 0; r < 4; ++r)
            tyv[kg * 4 + r] = trj[2 * (k0w + kg * 16 + quad * 4 + r) + 1];
    SCHED0();

    // ---- prefetch channel 2cg: both 32KB halves in flight during trig setup
    {
        const int c0 = cg * 2;
        ISSUE(c0, 0);
        ISSUE(c0, 1);
    }
    SCHED0();

    // ---- A fragments (px) via incremental rotation + packed bf16 cvt:
    // A[m][x = 32*t4 + 8*quad + j]; theta(x) = d1*(x-64) pi-units, d1 = -trjx/64
    bf16x8 pxr[2][4], pxi[2][4];
    #pragma unroll
    for (int kg = 0; kg < 2; ++kg) {
        const float d1 = -trjx[kg] * (1.0f / 64.0f);
        float s1, c1;  sincospif(d1, &s1, &c1);            // rot per +1 x
        float s32, c32; sincospif(d1 * 32.0f, &s32, &c32); // rot per +32 x (t4 step)
        float ps, pc;  sincospif(d1 * (float)(8 * quad - 64), &ps, &pc);
        #pragma unroll
        for (int t4 = 0; t4 < 4; ++t4) {
            float qc = pc, qs = ps;
            float fc[8], fs[8];
            #pragma unroll
            for (int j = 0; j < 8; ++j) {
                fc[j] = qc; fs[j] = qs;
                if (j < 7) {
                    float tq = qc * c1 - qs * s1;
                    qs = fmaf(qc, s1, qs * c1);
                    qc = tq;
                }
            }
            uint32_t* pr = (uint32_t*)&pxr[kg][t4];
            uint32_t* pi = (uint32_t*)&pxi[kg][t4];
            #pragma unroll
            for (int p = 0; p < 4; ++p) {
                pr[p] = pkbf(fc[2 * p], fc[2 * p + 1]);
                pi[p] = pkbf(fs[2 * p], fs[2 * p + 1]);
            }
            if (t4 < 3) {
                float tp = pc * c32 - ps * s32;
                ps = fmaf(pc, s32, ps * c32);
                pc = tp;
            }
        }
    }

    // ---- stage-2 rotor init. Lane element idx=(kg,r): k = k0w+kg*16+quad*4+r,
    // y = ct*8 + ybase, ybase = m>>1. (cb,sb) = cos/sin(pi * -ty*(y-64)/64);
    // per-ct step rotor (dr,di) = cos/sin(pi * -ty/8). Parity-independent.
    const int ybase = m >> 1;
    float cb0[8], sb0[8], dr[8], di[8];
    #pragma unroll
    for (int idx = 0; idx < 8; ++idx) {
        float ty = tyv[idx];
        float sbv, cbv; sincospif(-ty * (float)(ybase - 64) * (1.0f / 64.0f), &sbv, &cbv);
        cb0[idx] = cbv; sb0[idx] = sbv;
        float sd, cd; sincospif(-ty * 0.125f, &sd, &cd);
        dr[idx] = cd; di[idx] = sd;
    }

    // two pre-XOR'd LDS bases: addr(ct,t4) = (t4&1 ? po : pe)
    //                                        + 4096*ct + 128*(t4>>1)
    const int A0 = 256 * m + 16 * quad;
    const int Mx = 16 * (m & 7);
    const char* pe = (const char*)&Bl[0] + (A0 ^ Mx);
    const char* po = (const char*)&Bl[0] + ((A0 + 64) ^ Mx);
    const f32x4 ZER = {0.f, 0.f, 0.f, 0.f};

    float F[8], G[8], cb[8], sb[8];

    #pragma unroll 1
    for (int cc = 0; cc < 2; ++cc) {
        const int c = cg * 2 + cc;
        #pragma unroll
        for (int i = 0; i < 8; ++i) {
            F[i] = 0.f; G[i] = 0.f; cb[i] = cb0[i]; sb[i] = sb0[i];
        }

        // === buf0 ready ===
        if (cc == 0) { asm volatile("s_waitcnt vmcnt(8)" ::: "memory"); }
        else         { asm volatile("s_waitcnt vmcnt(0)" ::: "memory"); }
        SCHED0(); SBAR(); SCHED0();

        RUN8(0);   // ct 0..7 from buf0

        // === buf0 read-done; refill it with next channel's half0 ===
        asm volatile("s_waitcnt lgkmcnt(0)" ::: "memory");
        SCHED0(); SBAR(); SCHED0();
        if (cc == 0) { ISSUE(cg * 2 + 1, 0); }
        SCHED0();

        // === buf1 ready ===
        if (cc == 0) { asm volatile("s_waitcnt vmcnt(8)" ::: "memory"); }
        else         { asm volatile("s_waitcnt vmcnt(0)" ::: "memory"); }
        SCHED0(); SBAR(); SCHED0();

        RUN8(8);   // ct 8..15 from buf1

        // === buf1 read-done; refill with next channel's half1 ===
        asm volatile("s_waitcnt lgkmcnt(0)" ::: "memory");
        SCHED0(); SBAR(); SCHED0();
        if (cc == 0) { ISSUE(cg * 2 + 1, 1); }
        SCHED0();

        // epilogue: per-lane parity assignment, 16-lane DPP reduction (VALU)
        #pragma unroll
        for (int idx = 0; idx < 8; ++idx) {
            float kre_p = spar ? -G[idx] : F[idx];
            float kim_p = spar ?  F[idx] : G[idx];
            float kre_s = dpp_sum16(kre_p);
            float kim_s = dpp_sum16(kim_p);
            if (m == 0) {
                int kg = idx >> 2, r = idx & 3;
                int k = k0w + kg * 16 + quad * 4 + r;
                out[(size_t)c * KPTS + k]                      = kre_s;
                out[(size_t)NCH * KPTS + (size_t)c * KPTS + k] = kim_s;
            }
        }
    }
}

extern "C" void kernel_launch(void* const* d_in, const int* in_sizes, int n_in,
                              void* d_out, int out_size, void* d_ws, size_t ws_size,
                              hipStream_t stream)
{
    const float* img_real = (const float*)d_in[0];  // (8,128,128) fp32
    const float* img_imag = (const float*)d_in[1];  // (8,128,128) fp32
    const float* trj      = (const float*)d_in[2];  // (16384,2) fp32
    float* out = (float*)d_out;                      // planar: re block then im block
    unsigned short* B_pre = (unsigned short*)d_ws;   // 512 KB bf16 pre-swizzled img

    prep_kernel<<<128, 256, 0, stream>>>(img_real, img_imag, B_pre);
    nudft_mfma_kernel<<<dim3(128, 4), 256, 0, stream>>>(trj, B_pre, out);
}